// Round 7
// baseline (416.833 us; speedup 1.0000x reference)
//
#include <hip/hip_runtime.h>

#define Bg   128
#define NPG  512
#define EPGc 8192
#define Etot (Bg*EPGc)
#define DOUTc 10
#define K1c  410
#define K2c  328
#define N0c  (Bg*NPG)
#define N1c  (Bg*K1c)
#define N2c  (Bg*K2c)
#define EPSc 1e-5f

// ---------------- layer-0 graph prep + fused x graph-sum ----------------
// block g: LDS in-degree count -> dinv -> scan -> packed CSR scatter, plus
// global_add_pool(x) for readout slice 0 (written directly, no atomics/zero-init).
static __global__ __launch_bounds__(512) void k_prep0(const int* __restrict__ src,
                                                      const int* __restrict__ dst,
                                                      const float* __restrict__ x,
                                                      float* __restrict__ dinv,
                                                      int* __restrict__ rp,
                                                      int2* __restrict__ e2,
                                                      float* __restrict__ pooled0) {
  __shared__ int    cnt[NPG];
  __shared__ float  sdv[NPG];
  __shared__ int    srp[NPG];
  __shared__ int    sbuf[512];
  __shared__ float4 xred[512];
  int g = blockIdx.x, tid = threadIdx.x;
  cnt[tid] = 0;
  {  // x-sum partials: thread = (row-quarter rq, float4-col c4)
    int c4 = tid & 31, rq = tid >> 5;
    float4 a = make_float4(0.f, 0.f, 0.f, 0.f);
    const float4* xp = (const float4*)(x + (size_t)g * NPG * 128);
    for (int r = rq; r < NPG; r += 16) {
      float4 v = xp[r * 32 + c4];
      a.x += v.x; a.y += v.y; a.z += v.z; a.w += v.w;
    }
    xred[tid] = a;
  }
  __syncthreads();
  if (tid < 32) {
    float4 a = make_float4(0.f, 0.f, 0.f, 0.f);
    for (int q = 0; q < 16; ++q) {
      float4 v = xred[q * 32 + tid];
      a.x += v.x; a.y += v.y; a.z += v.z; a.w += v.w;
    }
    ((float4*)&pooled0[g * 128])[tid] = a;
  }
  const int* sp = src + (size_t)g * EPGc;
  const int* dp = dst + (size_t)g * EPGc;
  for (int e = tid; e < EPGc; e += 512) atomicAdd(&cnt[dp[e] - g * NPG], 1);
  __syncthreads();
  int c = cnt[tid];
  float dv = 1.0f / sqrtf(1.0f + (float)c);
  sdv[tid] = dv;
  dinv[g * NPG + tid] = dv;
  sbuf[tid] = c;
  __syncthreads();
  for (int off = 1; off < 512; off <<= 1) {
    int t = (tid >= off) ? sbuf[tid - off] : 0;
    __syncthreads();
    sbuf[tid] += t;
    __syncthreads();
  }
  srp[tid] = sbuf[tid] - c;
  rp[g * (NPG + 1) + tid] = sbuf[tid] - c;
  if (tid == 511) rp[g * (NPG + 1) + NPG] = sbuf[511];
  cnt[tid] = 0;
  __syncthreads();
  for (int e = tid; e < EPGc; e += 512) {
    int s = sp[e], d = dp[e];
    int dl = d - g * NPG;
    int pos = srp[dl] + atomicAdd(&cnt[dl], 1);
    e2[(size_t)g * EPGc + pos] =
        make_int2(s, __float_as_int(sdv[s - g * NPG] * sdv[dl]));
  }
}

// ---------------- GEMM: Y[M x 128] = X[M x 128] @ W[128 x 128] ----------------
// LDS-throughput bound at ~43us (0 conflicts); see round-6 notes. MFMA is the next step.
static __global__ __launch_bounds__(512) void k_gemm2(const float* __restrict__ X,
                                                      const float* __restrict__ W,
                                                      float* __restrict__ Y, int M) {
  __shared__ float ws[128 * 128];
  __shared__ float xs[128 * 132];
  int tid = threadIdx.x;
  for (int i = tid; i < 4096; i += 512) ((float4*)ws)[i] = ((const float4*)W)[i];
  int row0 = blockIdx.x * 128;
  for (int i = tid; i < 4096; i += 512) {
    int r = i >> 5, kq = i & 31;
    float4 v = ((const float4*)X)[(size_t)(row0 + r) * 32 + kq];
    *(float4*)&xs[r * 132 + kq * 4] = v;
  }
  __syncthreads();
  int tx = tid & 15, ty = tid >> 4;
  float acc[4][8];
#pragma unroll
  for (int i = 0; i < 4; ++i)
#pragma unroll
    for (int j = 0; j < 8; ++j) acc[i][j] = 0.f;
  for (int k = 0; k < 128; k += 4) {
    float4 xr[4];
#pragma unroll
    for (int i = 0; i < 4; ++i) xr[i] = *(const float4*)&xs[(ty * 4 + i) * 132 + k];
    const float* xf = (const float*)xr;
#pragma unroll
    for (int kk = 0; kk < 4; ++kk) {
      float4 wa = *(const float4*)&ws[(k + kk) * 128 + tx * 4];
      float4 wb = *(const float4*)&ws[(k + kk) * 128 + 64 + tx * 4];
#pragma unroll
      for (int i = 0; i < 4; ++i) {
        float xv = xf[i * 4 + kk];
        acc[i][0] += xv * wa.x; acc[i][1] += xv * wa.y;
        acc[i][2] += xv * wa.z; acc[i][3] += xv * wa.w;
        acc[i][4] += xv * wb.x; acc[i][5] += xv * wb.y;
        acc[i][6] += xv * wb.z; acc[i][7] += xv * wb.w;
      }
    }
  }
#pragma unroll
  for (int i = 0; i < 4; ++i) {
    int row = row0 + ty * 4 + i;
    float4 o1 = make_float4(acc[i][0], acc[i][1], acc[i][2], acc[i][3]);
    float4 o2 = make_float4(acc[i][4], acc[i][5], acc[i][6], acc[i][7]);
    ((float4*)Y)[(size_t)row * 32 + tx] = o1;
    ((float4*)Y)[(size_t)row * 32 + 16 + tx] = o2;
  }
}

// GCN aggregation: L2 gather, x8-unrolled edge MLP, fused score GEMV.
template <int NPER, int RG>
static __global__ __launch_bounds__(256) void k_agg3(const float* __restrict__ h0,
                                                     const float* __restrict__ dinv,
                                                     const float* __restrict__ bias,
                                                     const int* __restrict__ rp,
                                                     const int2* __restrict__ e2,
                                                     const float* __restrict__ sw,
                                                     float* __restrict__ h1,
                                                     float* __restrict__ spre) {
  int tid = threadIdx.x;
  int hw = tid >> 5, l = tid & 31;
  int b = blockIdx.x;
  int xcd = b & 7, slot = b >> 3;
  int g = xcd * 16 + (slot & 15);
  int rowgrp = slot >> 4;
  int li = rowgrp * 8 + hw;
  if (li >= NPER) return;
  int j = g * NPER + li;
  const int* rpg = rp + g * (NPER + 1);
  int start = rpg[li], end = rpg[li + 1];
  const int2* ep = e2 + (size_t)g * EPGc;
  float di = dinv[j];
  float sc = di * di;
  float4 acc = *(const float4*)&h0[(size_t)j * 128 + l * 4];
  float4 bb = ((const float4*)bias)[l];
  acc.x = acc.x * sc + bb.x; acc.y = acc.y * sc + bb.y;
  acc.z = acc.z * sc + bb.z; acc.w = acc.w * sc + bb.w;
  int e = start;
  for (; e + 8 <= end; e += 8) {
    int2 p[8];
#pragma unroll
    for (int q = 0; q < 8; ++q) p[q] = ep[e + q];
    float4 v[8];
#pragma unroll
    for (int q = 0; q < 8; ++q) v[q] = *(const float4*)&h0[(size_t)p[q].x * 128 + l * 4];
#pragma unroll
    for (int q = 0; q < 8; ++q) {
      float c = __int_as_float(p[q].y);
      acc.x += v[q].x * c; acc.y += v[q].y * c;
      acc.z += v[q].z * c; acc.w += v[q].w * c;
    }
  }
  for (; e + 4 <= end; e += 4) {
    int2 p0 = ep[e], p1 = ep[e + 1], p2 = ep[e + 2], p3 = ep[e + 3];
    float4 v0 = *(const float4*)&h0[(size_t)p0.x * 128 + l * 4];
    float4 v1 = *(const float4*)&h0[(size_t)p1.x * 128 + l * 4];
    float4 v2 = *(const float4*)&h0[(size_t)p2.x * 128 + l * 4];
    float4 v3 = *(const float4*)&h0[(size_t)p3.x * 128 + l * 4];
    float c0 = __int_as_float(p0.y), c1 = __int_as_float(p1.y);
    float c2 = __int_as_float(p2.y), c3 = __int_as_float(p3.y);
    acc.x += v0.x * c0 + v1.x * c1 + v2.x * c2 + v3.x * c3;
    acc.y += v0.y * c0 + v1.y * c1 + v2.y * c2 + v3.y * c3;
    acc.z += v0.z * c0 + v1.z * c1 + v2.z * c2 + v3.z * c3;
    acc.w += v0.w * c0 + v1.w * c1 + v2.w * c2 + v3.w * c3;
  }
  for (; e < end; ++e) {
    int2 pp = ep[e];
    float c = __int_as_float(pp.y);
    float4 v = *(const float4*)&h0[(size_t)pp.x * 128 + l * 4];
    acc.x += v.x * c; acc.y += v.y * c; acc.z += v.z * c; acc.w += v.w * c;
  }
  ((float4*)&h1[(size_t)j * 128])[l] = acc;
  float4 w4 = ((const float4*)sw)[l];
  float pr = acc.x * w4.x + acc.y * w4.y + acc.z * w4.z + acc.w * w4.w;
#pragma unroll
  for (int off = 16; off; off >>= 1) pr += __shfl_xor(pr, off, 64);
  if (l == 0) spre[j] = pr;
}

// ---------------- layer-1 mega-fusion ----------------
// block g: score (spre in LDS) -> bitonic top-K1 -> remap -> edge filter/count/
// scan/CSR rebuild (into dinv2/rp2/e2) -> fused poolbn + graph-sum (pooled slice 1,
// written directly: one block owns the whole graph).
static __global__ __launch_bounds__(512) void k_repool1(const float* __restrict__ spre,
                                                        const float* __restrict__ dinv,
                                                        const float* __restrict__ sb,
                                                        const int* __restrict__ rp,
                                                        int2* __restrict__ e2,
                                                        const int* __restrict__ src,
                                                        const int* __restrict__ dst,
                                                        const float* __restrict__ h1,
                                                        const float* __restrict__ gg,
                                                        const float* __restrict__ bbn,
                                                        const float* __restrict__ mm,
                                                        const float* __restrict__ vv,
                                                        float* __restrict__ xp1,
                                                        float* __restrict__ dinv2,
                                                        int* __restrict__ rp2,
                                                        float* __restrict__ pooled1) {
  __shared__ float ss[NPG];
  __shared__ float sc[512];
  __shared__ int   sidx[512];
  __shared__ short rmp[NPG];
  __shared__ int   cnt[K1c];
  __shared__ float sdv[K1c];
  __shared__ int   srp[K1c];
  __shared__ int   sbuf[512];
  __shared__ float pbuf[4 * 128];
  int g = blockIdx.x, tid = threadIdx.x;
  ss[tid] = spre[g * NPG + tid];
  rmp[tid] = -1;
  __syncthreads();
  {  // score: sv = spre*dinv^2 + b + sum cval*spre[col], gathers from LDS
    const int* rpg = rp + g * (NPG + 1);
    int st = rpg[tid], en = rpg[tid + 1];
    const int2* ep = e2 + (size_t)g * EPGc;
    float di = dinv[g * NPG + tid];
    float acc = ss[tid] * di * di + sb[0];
    int e = st;
    for (; e + 4 <= en; e += 4) {
      int2 p0 = ep[e], p1 = ep[e + 1], p2 = ep[e + 2], p3 = ep[e + 3];
      acc += ss[p0.x - g * NPG] * __int_as_float(p0.y) +
             ss[p1.x - g * NPG] * __int_as_float(p1.y) +
             ss[p2.x - g * NPG] * __int_as_float(p2.y) +
             ss[p3.x - g * NPG] * __int_as_float(p3.y);
    }
    for (; e < en; ++e) { int2 pp = ep[e]; acc += ss[pp.x - g * NPG] * __int_as_float(pp.y); }
    sc[tid] = acc;
    sidx[tid] = tid;
  }
  __syncthreads();
  for (int kk = 2; kk <= 512; kk <<= 1) {
    for (int j = kk >> 1; j > 0; j >>= 1) {
      int i = tid, p = i ^ j;
      if (p > i) {
        bool up = ((i & kk) == 0);
        float si = sc[i], sp2 = sc[p];
        if (up ? (si < sp2) : (si > sp2)) {
          sc[i] = sp2; sc[p] = si;
          int t = sidx[i]; sidx[i] = sidx[p]; sidx[p] = t;
        }
      }
      __syncthreads();
    }
  }
  if (tid < K1c) { rmp[sidx[tid]] = (short)tid; cnt[tid] = 0; }
  __syncthreads();
  const int* sp = src + (size_t)g * EPGc;
  const int* dp = dst + (size_t)g * EPGc;
  for (int e = tid; e < EPGc; e += 512) {
    int s = rmp[sp[e] - g * NPG];
    int d = rmp[dp[e] - g * NPG];
    if ((s | d) >= 0) atomicAdd(&cnt[d], 1);
  }
  __syncthreads();
  int c = (tid < K1c) ? cnt[tid] : 0;
  if (tid < K1c) {
    float dv = 1.0f / sqrtf(1.0f + (float)c);
    sdv[tid] = dv;
    dinv2[g * K1c + tid] = dv;
  }
  sbuf[tid] = c;
  __syncthreads();
  for (int off = 1; off < 512; off <<= 1) {
    int t = (tid >= off) ? sbuf[tid - off] : 0;
    __syncthreads();
    sbuf[tid] += t;
    __syncthreads();
  }
  if (tid < K1c) { srp[tid] = sbuf[tid] - c; rp2[g * (K1c + 1) + tid] = sbuf[tid] - c; cnt[tid] = 0; }
  if (tid == 511) rp2[g * (K1c + 1) + K1c] = sbuf[511];
  __syncthreads();
  for (int e = tid; e < EPGc; e += 512) {
    int s = rmp[sp[e] - g * NPG];
    int d = rmp[dp[e] - g * NPG];
    if ((s | d) >= 0) {
      int pos = srp[d] + atomicAdd(&cnt[d], 1);
      e2[(size_t)g * EPGc + pos] = make_int2(g * K1c + s, __float_as_int(sdv[s] * sdv[d]));
    }
  }
  // fused poolbn + graph-sum (sc/sidx stable since sort)
  int f = tid & 127, rsub = tid >> 7;
  float G = gg[f], Bb = bbn[f], Mm = mm[f];
  float inv = 1.0f / sqrtf(vv[f] + EPSc);
  float acc = 0.f;
  for (int r = rsub; r < K1c; r += 4) {
    int old = g * NPG + sidx[r];
    float t = tanhf(sc[r]);
    float val = h1[(size_t)old * 128 + f] * t;
    float o = fmaxf(G * (val - Mm) * inv + Bb, 0.f);
    xp1[((size_t)g * K1c + r) * 128 + f] = o;
    acc += o;
  }
  pbuf[rsub * 128 + f] = acc;
  __syncthreads();
  if (tid < 128)
    pooled1[g * 128 + tid] = pbuf[tid] + pbuf[128 + tid] + pbuf[256 + tid] + pbuf[384 + tid];
}

// ---------------- layer-2 pool: score + topk + poolbn + graph-sum --------------
static __global__ __launch_bounds__(512) void k_pool2(const float* __restrict__ spre,
                                                      const float* __restrict__ dinv2,
                                                      const float* __restrict__ sb,
                                                      const int* __restrict__ rp2,
                                                      const int2* __restrict__ e2,
                                                      const float* __restrict__ h2,
                                                      const float* __restrict__ gg,
                                                      const float* __restrict__ bbn,
                                                      const float* __restrict__ mm,
                                                      const float* __restrict__ vv,
                                                      float* __restrict__ pooled2) {
  __shared__ float ss[K1c];
  __shared__ float sc[512];
  __shared__ int   sidx[512];
  __shared__ float pbuf[4 * 128];
  int g = blockIdx.x, tid = threadIdx.x;
  if (tid < K1c) ss[tid] = spre[g * K1c + tid];
  __syncthreads();
  if (tid < K1c) {
    const int* rpg = rp2 + g * (K1c + 1);
    int st = rpg[tid], en = rpg[tid + 1];
    const int2* ep = e2 + (size_t)g * EPGc;
    float di = dinv2[g * K1c + tid];
    float acc = ss[tid] * di * di + sb[0];
    int e = st;
    for (; e + 4 <= en; e += 4) {
      int2 p0 = ep[e], p1 = ep[e + 1], p2 = ep[e + 2], p3 = ep[e + 3];
      acc += ss[p0.x - g * K1c] * __int_as_float(p0.y) +
             ss[p1.x - g * K1c] * __int_as_float(p1.y) +
             ss[p2.x - g * K1c] * __int_as_float(p2.y) +
             ss[p3.x - g * K1c] * __int_as_float(p3.y);
    }
    for (; e < en; ++e) { int2 pp = ep[e]; acc += ss[pp.x - g * K1c] * __int_as_float(pp.y); }
    sc[tid] = acc;
  } else {
    sc[tid] = -3.402823466e38f;
  }
  sidx[tid] = tid;
  __syncthreads();
  for (int kk = 2; kk <= 512; kk <<= 1) {
    for (int j = kk >> 1; j > 0; j >>= 1) {
      int i = tid, p = i ^ j;
      if (p > i) {
        bool up = ((i & kk) == 0);
        float si = sc[i], sp2 = sc[p];
        if (up ? (si < sp2) : (si > sp2)) {
          sc[i] = sp2; sc[p] = si;
          int t = sidx[i]; sidx[i] = sidx[p]; sidx[p] = t;
        }
      }
      __syncthreads();
    }
  }
  int f = tid & 127, rsub = tid >> 7;
  float G = gg[f], Bb = bbn[f], Mm = mm[f];
  float inv = 1.0f / sqrtf(vv[f] + EPSc);
  float acc = 0.f;
  for (int r = rsub; r < K2c; r += 4) {
    int old = g * K1c + sidx[r];
    float t = tanhf(sc[r]);
    float val = h2[(size_t)old * 128 + f] * t;
    float o = fmaxf(G * (val - Mm) * inv + Bb, 0.f);
    acc += o;
  }
  pbuf[rsub * 128 + f] = acc;
  __syncthreads();
  if (tid < 128)
    pooled2[g * 128 + tid] = pbuf[tid] + pbuf[128 + tid] + pbuf[256 + tid] + pbuf[384 + tid];
}

static __global__ void k_final(const float* __restrict__ pooled,
                               const float* __restrict__ w0, const float* __restrict__ b0,
                               const float* __restrict__ w1, const float* __restrict__ b1,
                               const float* __restrict__ w2, const float* __restrict__ b2,
                               float* __restrict__ out) {
  int t = blockIdx.x * 256 + threadIdx.x;
  if (t >= Bg * DOUTc) return;
  int g = t / DOUTc, o = t - g * DOUTc;
  const float* p0 = pooled + g * 128;
  const float* p1 = pooled + Bg * 128 + g * 128;
  const float* p2 = pooled + 2 * Bg * 128 + g * 128;
  float acc = b0[o] + b1[o] + b2[o];
  for (int k = 0; k < 128; ++k)
    acc += p0[k] * w0[o * 128 + k] + p1[k] * w1[o * 128 + k] + p2[k] * w2[o * 128 + k];
  out[t] = acc;
}

extern "C" void kernel_launch(void* const* d_in, const int* in_sizes, int n_in,
                              void* d_out, int out_size, void* d_ws, size_t ws_size,
                              hipStream_t stream) {
  (void)in_sizes; (void)n_in; (void)out_size; (void)ws_size;
  const float* x    = (const float*)d_in[0];
  const int*   ei   = (const int*)d_in[1];
  const int*   src0 = ei;
  const int*   dst0 = ei + Etot;
  const float* c1W = (const float*)d_in[2];  const float* c1b = (const float*)d_in[3];
  const float* c2W = (const float*)d_in[4];  const float* c2b = (const float*)d_in[5];
  const float* s1W = (const float*)d_in[6];  const float* s1b = (const float*)d_in[7];
  const float* s2W = (const float*)d_in[8];  const float* s2b = (const float*)d_in[9];
  const float* bn1g = (const float*)d_in[10]; const float* bn1b = (const float*)d_in[11];
  const float* bn1m = (const float*)d_in[12]; const float* bn1v = (const float*)d_in[13];
  const float* bn2g = (const float*)d_in[14]; const float* bn2b = (const float*)d_in[15];
  const float* bn2m = (const float*)d_in[16]; const float* bn2v = (const float*)d_in[17];
  const float* l0W = (const float*)d_in[18]; const float* l0b = (const float*)d_in[19];
  const float* l1W = (const float*)d_in[20]; const float* l1b = (const float*)d_in[21];
  const float* l2W = (const float*)d_in[22]; const float* l2b = (const float*)d_in[23];
  float* out = (float*)d_out;

  char* p = (char*)d_ws;
  auto alloc = [&](size_t bytes) { char* q = p; p += (bytes + 255) & ~(size_t)255; return q; };
  float* h0    = (float*)alloc((size_t)N0c * 128 * 4);   // layer1 reuses as g1
  float* h1    = (float*)alloc((size_t)N0c * 128 * 4);   // layer1 reuses as h2
  float* xp1   = (float*)alloc((size_t)N1c * 128 * 4);
  float* dinv  = (float*)alloc((size_t)N0c * 4);
  float* dinv2 = (float*)alloc((size_t)N1c * 4);
  int*   rp    = (int*)alloc((size_t)Bg * (NPG + 1) * 4);
  int*   rp2   = (int*)alloc((size_t)Bg * (K1c + 1) * 4);
  int2*  e2    = (int2*)alloc((size_t)Etot * 8);
  float* spre  = (float*)alloc((size_t)N0c * 4);
  float* pooled= (float*)alloc((size_t)3 * Bg * 128 * 4);

  dim3 b256(256), b512(512);

  // ---------------- layer 0 ----------------
  k_prep0<<<Bg, b512, 0, stream>>>(src0, dst0, x, dinv, rp, e2, pooled);
  k_gemm2<<<N0c / 128, b512, 0, stream>>>(x, c1W, h0, N0c);
  k_agg3<NPG, 64><<<128 * 64, b256, 0, stream>>>(h0, dinv, c1b, rp, e2, s1W, h1, spre);
  k_repool1<<<Bg, b512, 0, stream>>>(spre, dinv, s1b, rp, e2, src0, dst0, h1,
                                     bn1g, bn1b, bn1m, bn1v, xp1, dinv2, rp2,
                                     pooled + Bg * 128);

  // ---------------- layer 1 ----------------
  float* g1 = h0;   // h0 dead after layer-0 agg
  float* h2 = h1;   // h1 dead after repool1
  k_gemm2<<<N1c / 128, b512, 0, stream>>>(xp1, c2W, g1, N1c);
  k_agg3<K1c, 52><<<128 * 52, b256, 0, stream>>>(g1, dinv2, c2b, rp2, e2, s2W, h2, spre);
  k_pool2<<<Bg, b512, 0, stream>>>(spre, dinv2, s2b, rp2, e2, h2,
                                   bn2g, bn2b, bn2m, bn2v, pooled + 2 * Bg * 128);

  // ---------------- readout ----------------
  k_final<<<(Bg * DOUTc + 255) / 256, b256, 0, stream>>>(pooled, l0W, l0b, l1W, l1b, l2W, l2b, out);
}

// Round 8
// 385.127 us; speedup vs baseline: 1.0823x; 1.0823x over previous
//
#include <hip/hip_runtime.h>

#define Bg   128
#define NPG  512
#define EPGc 8192
#define Etot (Bg*EPGc)
#define DOUTc 10
#define K1c  410
#define K2c  328
#define N0c  (Bg*NPG)
#define N1c  (Bg*K1c)
#define N2c  (Bg*K2c)
#define EPSc 1e-5f

typedef __attribute__((ext_vector_type(8))) short s8v;   // 8 bf16 (4 VGPRs)
typedef __attribute__((ext_vector_type(4))) float f4v;   // mfma acc

static __device__ __forceinline__ unsigned short bf_rne(float x) {
  unsigned u = __float_as_uint(x);
  u += 0x7FFFu + ((u >> 16) & 1u);       // round-to-nearest-even
  return (unsigned short)(u >> 16);
}
static __device__ __forceinline__ float bf_f(unsigned short h) {
  return __uint_as_float(((unsigned)h) << 16);
}

// ---------------- pack W1,W2 into MFMA B-fragment layout, bf16 hi/lo ----------
// B frag for 16x16x32: lane holds B[k=quad*8+j][n=lane&15]. packed[(kk*8+t)*512
// + lane*8 + j]; hi at +0, lo at +16384; W2 at +32768. One-time, ~2us.
static __global__ void k_packW(const float* __restrict__ W1,
                               const float* __restrict__ W2,
                               unsigned short* __restrict__ pk) {
  int i = blockIdx.x * 256 + threadIdx.x;
  if (i >= 32768) return;
  const float* W = (i < 16384) ? W1 : W2;
  unsigned short* d = pk + ((i < 16384) ? 0 : 32768);
  int ii = i & 16383;
  int grp = ii >> 9, lane = (ii >> 3) & 63, j = ii & 7;
  int kk = grp >> 3, t = grp & 7;
  int k = kk * 32 + (lane >> 4) * 8 + j;
  int n = t * 16 + (lane & 15);
  float w = W[k * 128 + n];
  unsigned short hi = bf_rne(w);
  d[ii] = hi;
  d[16384 + ii] = bf_rne(w - bf_f(hi));
}

// ---------------- layer-0 graph prep + fused x graph-sum ----------------
static __global__ __launch_bounds__(512) void k_prep0(const int* __restrict__ src,
                                                      const int* __restrict__ dst,
                                                      const float* __restrict__ x,
                                                      float* __restrict__ dinv,
                                                      int* __restrict__ rp,
                                                      int2* __restrict__ e2,
                                                      float* __restrict__ pooled) {
  __shared__ int    cnt[NPG];
  __shared__ float  sdv[NPG];
  __shared__ int    srp[NPG];
  __shared__ int    sbuf[512];
  __shared__ float4 xred[512];
  int g = blockIdx.x, tid = threadIdx.x;
  cnt[tid] = 0;
  if (tid < 128) {                       // zero slices 1,2 (atomic poolbn targets)
    pooled[Bg * 128 + g * 128 + tid] = 0.f;
    pooled[2 * Bg * 128 + g * 128 + tid] = 0.f;
  }
  {  // x-sum partials
    int c4 = tid & 31, rq = tid >> 5;
    float4 a = make_float4(0.f, 0.f, 0.f, 0.f);
    const float4* xp = (const float4*)(x + (size_t)g * NPG * 128);
    for (int r = rq; r < NPG; r += 16) {
      float4 v = xp[r * 32 + c4];
      a.x += v.x; a.y += v.y; a.z += v.z; a.w += v.w;
    }
    xred[tid] = a;
  }
  __syncthreads();
  if (tid < 32) {
    float4 a = make_float4(0.f, 0.f, 0.f, 0.f);
    for (int q = 0; q < 16; ++q) {
      float4 v = xred[q * 32 + tid];
      a.x += v.x; a.y += v.y; a.z += v.z; a.w += v.w;
    }
    ((float4*)&pooled[g * 128])[tid] = a;
  }
  const int* sp = src + (size_t)g * EPGc;
  const int* dp = dst + (size_t)g * EPGc;
  for (int e = tid; e < EPGc; e += 512) atomicAdd(&cnt[dp[e] - g * NPG], 1);
  __syncthreads();
  int c = cnt[tid];
  float dv = 1.0f / sqrtf(1.0f + (float)c);
  sdv[tid] = dv;
  dinv[g * NPG + tid] = dv;
  sbuf[tid] = c;
  __syncthreads();
  for (int off = 1; off < 512; off <<= 1) {
    int t = (tid >= off) ? sbuf[tid - off] : 0;
    __syncthreads();
    sbuf[tid] += t;
    __syncthreads();
  }
  srp[tid] = sbuf[tid] - c;
  rp[g * (NPG + 1) + tid] = sbuf[tid] - c;
  if (tid == 511) rp[g * (NPG + 1) + NPG] = sbuf[511];
  cnt[tid] = 0;
  __syncthreads();
  for (int e = tid; e < EPGc; e += 512) {
    int s = sp[e], d = dp[e];
    int dl = d - g * NPG;
    int pos = srp[dl] + atomicAdd(&cnt[dl], 1);
    e2[(size_t)g * EPGc + pos] =
        make_int2(s, __float_as_int(sdv[s - g * NPG] * sdv[dl]));
  }
}

// ---------------- MFMA GEMM: Y[M x 128] = X[M x 128] @ W (bf16 hi/lo split) ----
// Round-8: replaces the fp32-vector gemm2 (43us, LDS-throughput bound). 3 bf16
// MFMAs approximate the fp32 product to ~2^-17 rel. A frags straight from global
// (A[m=lane&15][k=quad*8+j] = 8 contiguous floats); packed W staged to LDS.
static __global__ __launch_bounds__(256) void k_gemm3(const float* __restrict__ X,
                                                      const unsigned short* __restrict__ pk,
                                                      float* __restrict__ Y) {
  __shared__ unsigned short wl[32768];   // 64 KB: hi[16384] + lo[16384]
  int tid = threadIdx.x;
  for (int i = tid; i < 4096; i += 256) ((int4*)wl)[i] = ((const int4*)pk)[i];
  int wv = tid >> 6, lane = tid & 63;
  int q = lane >> 4, m16 = lane & 15;
  size_t row = (size_t)blockIdx.x * 64 + wv * 16 + m16;
  s8v ahi[4], alo[4];
#pragma unroll
  for (int kk = 0; kk < 4; ++kk) {
    const float* xr = X + row * 128 + kk * 32 + q * 8;
    float4 a0 = *(const float4*)xr;
    float4 a1 = *(const float4*)(xr + 4);
    float av[8] = {a0.x, a0.y, a0.z, a0.w, a1.x, a1.y, a1.z, a1.w};
    union { unsigned short u[8]; s8v v; } H, L;
#pragma unroll
    for (int j = 0; j < 8; ++j) {
      unsigned short h = bf_rne(av[j]);
      H.u[j] = h;
      L.u[j] = bf_rne(av[j] - bf_f(h));
    }
    ahi[kk] = H.v; alo[kk] = L.v;
  }
  __syncthreads();
  int orow0 = blockIdx.x * 64 + wv * 16 + q * 4;
#pragma unroll
  for (int t = 0; t < 8; ++t) {
    f4v acc = {0.f, 0.f, 0.f, 0.f};
#pragma unroll
    for (int kk = 0; kk < 4; ++kk) {
      s8v bhi = *(const s8v*)&wl[(kk * 8 + t) * 512 + lane * 8];
      s8v blo = *(const s8v*)&wl[16384 + (kk * 8 + t) * 512 + lane * 8];
      acc = __builtin_amdgcn_mfma_f32_16x16x32_bf16(ahi[kk], bhi, acc, 0, 0, 0);
      acc = __builtin_amdgcn_mfma_f32_16x16x32_bf16(alo[kk], bhi, acc, 0, 0, 0);
      acc = __builtin_amdgcn_mfma_f32_16x16x32_bf16(ahi[kk], blo, acc, 0, 0, 0);
    }
#pragma unroll
    for (int r = 0; r < 4; ++r)
      Y[(size_t)(orow0 + r) * 128 + t * 16 + m16] = acc[r];   // C/D: col=lane&15,row=q*4+r
  }
}

// GCN aggregation: L2 gather, x8-unrolled edge MLP, fused score GEMV.
template <int NPER, int RG>
static __global__ __launch_bounds__(256) void k_agg3(const float* __restrict__ h0,
                                                     const float* __restrict__ dinv,
                                                     const float* __restrict__ bias,
                                                     const int* __restrict__ rp,
                                                     const int2* __restrict__ e2,
                                                     const float* __restrict__ sw,
                                                     float* __restrict__ h1,
                                                     float* __restrict__ spre) {
  int tid = threadIdx.x;
  int hw = tid >> 5, l = tid & 31;
  int b = blockIdx.x;
  int xcd = b & 7, slot = b >> 3;
  int g = xcd * 16 + (slot & 15);
  int rowgrp = slot >> 4;
  int li = rowgrp * 8 + hw;
  if (li >= NPER) return;
  int j = g * NPER + li;
  const int* rpg = rp + g * (NPER + 1);
  int start = rpg[li], end = rpg[li + 1];
  const int2* ep = e2 + (size_t)g * EPGc;
  float di = dinv[j];
  float sc = di * di;
  float4 acc = *(const float4*)&h0[(size_t)j * 128 + l * 4];
  float4 bb = ((const float4*)bias)[l];
  acc.x = acc.x * sc + bb.x; acc.y = acc.y * sc + bb.y;
  acc.z = acc.z * sc + bb.z; acc.w = acc.w * sc + bb.w;
  int e = start;
  for (; e + 8 <= end; e += 8) {
    int2 p[8];
#pragma unroll
    for (int qq = 0; qq < 8; ++qq) p[qq] = ep[e + qq];
    float4 v[8];
#pragma unroll
    for (int qq = 0; qq < 8; ++qq) v[qq] = *(const float4*)&h0[(size_t)p[qq].x * 128 + l * 4];
#pragma unroll
    for (int qq = 0; qq < 8; ++qq) {
      float c = __int_as_float(p[qq].y);
      acc.x += v[qq].x * c; acc.y += v[qq].y * c;
      acc.z += v[qq].z * c; acc.w += v[qq].w * c;
    }
  }
  for (; e + 4 <= end; e += 4) {
    int2 p0 = ep[e], p1 = ep[e + 1], p2 = ep[e + 2], p3 = ep[e + 3];
    float4 v0 = *(const float4*)&h0[(size_t)p0.x * 128 + l * 4];
    float4 v1 = *(const float4*)&h0[(size_t)p1.x * 128 + l * 4];
    float4 v2 = *(const float4*)&h0[(size_t)p2.x * 128 + l * 4];
    float4 v3 = *(const float4*)&h0[(size_t)p3.x * 128 + l * 4];
    float c0 = __int_as_float(p0.y), c1 = __int_as_float(p1.y);
    float c2 = __int_as_float(p2.y), c3 = __int_as_float(p3.y);
    acc.x += v0.x * c0 + v1.x * c1 + v2.x * c2 + v3.x * c3;
    acc.y += v0.y * c0 + v1.y * c1 + v2.y * c2 + v3.y * c3;
    acc.z += v0.z * c0 + v1.z * c1 + v2.z * c2 + v3.z * c3;
    acc.w += v0.w * c0 + v1.w * c1 + v2.w * c2 + v3.w * c3;
  }
  for (; e < end; ++e) {
    int2 pp = ep[e];
    float c = __int_as_float(pp.y);
    float4 v = *(const float4*)&h0[(size_t)pp.x * 128 + l * 4];
    acc.x += v.x * c; acc.y += v.y * c; acc.z += v.z * c; acc.w += v.w * c;
  }
  ((float4*)&h1[(size_t)j * 128])[l] = acc;
  float4 w4 = ((const float4*)sw)[l];
  float pr = acc.x * w4.x + acc.y * w4.y + acc.z * w4.z + acc.w * w4.w;
#pragma unroll
  for (int off = 16; off; off >>= 1) pr += __shfl_xor(pr, off, 64);
  if (l == 0) spre[j] = pr;
}

// s[j] = spre[j]*dinv^2 + b + sum_e cval*spre[col]  (grid-parallel; round-7's
// fused version at 128 blocks was the regression)
template <int NPER>
static __global__ void k_score2(const float* __restrict__ spre, const float* __restrict__ dinv,
                                const float* __restrict__ bptr, const int* __restrict__ rp,
                                const int2* __restrict__ e2, float* __restrict__ s, int n) {
  int j = blockIdx.x * 256 + threadIdx.x;
  if (j >= n) return;
  int g = j / NPER, li = j - g * NPER;
  const int* rpg = rp + g * (NPER + 1);
  int start = rpg[li], end = rpg[li + 1];
  const int2* ep = e2 + (size_t)g * EPGc;
  float di = dinv[j];
  float acc = spre[j] * di * di + bptr[0];
  int e = start;
  for (; e + 4 <= end; e += 4) {
    int2 p0 = ep[e], p1 = ep[e + 1], p2 = ep[e + 2], p3 = ep[e + 3];
    float a0 = spre[p0.x], a1 = spre[p1.x], a2 = spre[p2.x], a3 = spre[p3.x];
    acc += a0 * __int_as_float(p0.y) + a1 * __int_as_float(p1.y) +
           a2 * __int_as_float(p2.y) + a3 * __int_as_float(p3.y);
  }
  for (; e < end; ++e) { int2 pp = ep[e]; acc += spre[pp.x] * __int_as_float(pp.y); }
  s[j] = acc;
}

// topk + remap + edge filter + CSR rebuild, per graph (slim: no score/poolbn)
template <int NPER, int K>
static __global__ __launch_bounds__(512) void k_repool(const float* __restrict__ sv,
                                                       const int* __restrict__ src,
                                                       const int* __restrict__ dst,
                                                       int* __restrict__ perm,
                                                       float* __restrict__ dinv2,
                                                       int* __restrict__ rp2,
                                                       int2* __restrict__ e2) {
  __shared__ float sc[512];
  __shared__ int   sidx[512];
  __shared__ short rmp[NPER];
  __shared__ int   cnt[K];
  __shared__ float sdv[K];
  __shared__ int   srp[K];
  __shared__ int   sbuf[512];
  int g = blockIdx.x, tid = threadIdx.x;
  sc[tid] = (tid < NPER) ? sv[g * NPER + tid] : -3.402823466e38f;
  sidx[tid] = tid;
  if (tid < NPER) rmp[tid] = -1;
  __syncthreads();
  for (int kk = 2; kk <= 512; kk <<= 1) {
    for (int j = kk >> 1; j > 0; j >>= 1) {
      int i = tid, p = i ^ j;
      if (p > i) {
        bool up = ((i & kk) == 0);
        float si = sc[i], sp2 = sc[p];
        if (up ? (si < sp2) : (si > sp2)) {
          sc[i] = sp2; sc[p] = si;
          int t = sidx[i]; sidx[i] = sidx[p]; sidx[p] = t;
        }
      }
      __syncthreads();
    }
  }
  if (tid < K) {
    perm[g * K + tid] = g * NPER + sidx[tid];
    rmp[sidx[tid]] = (short)tid;
    cnt[tid] = 0;
  }
  __syncthreads();
  const int* sp = src + (size_t)g * EPGc;
  const int* dp = dst + (size_t)g * EPGc;
  for (int e = tid; e < EPGc; e += 512) {
    int s = rmp[sp[e] - g * NPER];
    int d = rmp[dp[e] - g * NPER];
    if ((s | d) >= 0) atomicAdd(&cnt[d], 1);
  }
  __syncthreads();
  int c = (tid < K) ? cnt[tid] : 0;
  if (tid < K) {
    float dv = 1.0f / sqrtf(1.0f + (float)c);
    sdv[tid] = dv;
    dinv2[g * K + tid] = dv;
  }
  sbuf[tid] = c;
  __syncthreads();
  for (int off = 1; off < 512; off <<= 1) {
    int t = (tid >= off) ? sbuf[tid - off] : 0;
    __syncthreads();
    sbuf[tid] += t;
    __syncthreads();
  }
  if (tid < K) { srp[tid] = sbuf[tid] - c; rp2[g * (K + 1) + tid] = sbuf[tid] - c; cnt[tid] = 0; }
  if (tid == 511) rp2[g * (K + 1) + K] = sbuf[511];
  __syncthreads();
  for (int e = tid; e < EPGc; e += 512) {
    int s = rmp[sp[e] - g * NPER];
    int d = rmp[dp[e] - g * NPER];
    if ((s | d) >= 0) {
      int pos = srp[d] + atomicAdd(&cnt[d], 1);
      e2[(size_t)g * EPGc + pos] = make_int2(g * K + s, __float_as_int(sdv[s] * sdv[d]));
    }
  }
}

// plain per-graph top-K (layer 2 needs no edge rebuild)
template <int NPER, int K>
static __global__ __launch_bounds__(256) void k_topk(const float* __restrict__ s,
                                                     int* __restrict__ perm) {
  __shared__ float sc[512];
  __shared__ int   idx[512];
  int g = blockIdx.x, tid = threadIdx.x;
  for (int i = tid; i < 512; i += 256) {
    if (i < NPER) { sc[i] = s[g * NPER + i]; idx[i] = i; }
    else          { sc[i] = -3.402823466e38f; idx[i] = 0; }
  }
  __syncthreads();
  for (int kk = 2; kk <= 512; kk <<= 1) {
    for (int j = kk >> 1; j > 0; j >>= 1) {
      for (int base = 0; base < 512; base += 256) {
        int i = base + tid;
        int p = i ^ j;
        if (p > i) {
          bool up = ((i & kk) == 0);
          float si = sc[i], sp = sc[p];
          if (up ? (si < sp) : (si > sp)) {
            sc[i] = sp; sc[p] = si;
            int t = idx[i]; idx[i] = idx[p]; idx[p] = t;
          }
        }
      }
      __syncthreads();
    }
  }
  for (int r = tid; r < K; r += 256) perm[g * K + r] = g * NPER + idx[r];
}

// xp[j] = relu(bn(h[perm[j]]*tanh(s[perm[j]]))), fused graph-sum via one atomic
// per (block, feature). Grid Bg*CH -> full-machine parallel.
template <int NPER, int CH, bool WXP>
static __global__ __launch_bounds__(128) void k_poolbn(const float* __restrict__ h,
                                                       const float* __restrict__ s,
                                                       const int* __restrict__ perm,
                                                       const float* __restrict__ gg,
                                                       const float* __restrict__ bb,
                                                       const float* __restrict__ mm,
                                                       const float* __restrict__ vv,
                                                       float* __restrict__ xp,
                                                       float* __restrict__ pooledseg) {
  int g = blockIdx.x / CH, cidx = blockIdx.x - g * CH;
  int f = threadIdx.x;
  const int rows = (NPER + CH - 1) / CH;
  int r0 = cidx * rows, r1 = min(NPER, r0 + rows);
  float G = gg[f], Bb = bb[f], Mm = mm[f];
  float inv = 1.0f / sqrtf(vv[f] + EPSc);
  float acc = 0.f;
  for (int r = r0; r < r1; ++r) {
    int j = g * NPER + r;
    int old = perm[j];
    float t = tanhf(s[old]);
    float val = h[(size_t)old * 128 + f] * t;
    float o = fmaxf(G * (val - Mm) * inv + Bb, 0.f);
    if (WXP) xp[(size_t)j * 128 + f] = o;
    acc += o;
  }
  atomicAdd(&pooledseg[g * 128 + f], acc);
}

static __global__ void k_final(const float* __restrict__ pooled,
                               const float* __restrict__ w0, const float* __restrict__ b0,
                               const float* __restrict__ w1, const float* __restrict__ b1,
                               const float* __restrict__ w2, const float* __restrict__ b2,
                               float* __restrict__ out) {
  int t = blockIdx.x * 256 + threadIdx.x;
  if (t >= Bg * DOUTc) return;
  int g = t / DOUTc, o = t - g * DOUTc;
  const float* p0 = pooled + g * 128;
  const float* p1 = pooled + Bg * 128 + g * 128;
  const float* p2 = pooled + 2 * Bg * 128 + g * 128;
  float acc = b0[o] + b1[o] + b2[o];
  for (int k = 0; k < 128; ++k)
    acc += p0[k] * w0[o * 128 + k] + p1[k] * w1[o * 128 + k] + p2[k] * w2[o * 128 + k];
  out[t] = acc;
}

extern "C" void kernel_launch(void* const* d_in, const int* in_sizes, int n_in,
                              void* d_out, int out_size, void* d_ws, size_t ws_size,
                              hipStream_t stream) {
  (void)in_sizes; (void)n_in; (void)out_size; (void)ws_size;
  const float* x    = (const float*)d_in[0];
  const int*   ei   = (const int*)d_in[1];
  const int*   src0 = ei;
  const int*   dst0 = ei + Etot;
  const float* c1W = (const float*)d_in[2];  const float* c1b = (const float*)d_in[3];
  const float* c2W = (const float*)d_in[4];  const float* c2b = (const float*)d_in[5];
  const float* s1W = (const float*)d_in[6];  const float* s1b = (const float*)d_in[7];
  const float* s2W = (const float*)d_in[8];  const float* s2b = (const float*)d_in[9];
  const float* bn1g = (const float*)d_in[10]; const float* bn1b = (const float*)d_in[11];
  const float* bn1m = (const float*)d_in[12]; const float* bn1v = (const float*)d_in[13];
  const float* bn2g = (const float*)d_in[14]; const float* bn2b = (const float*)d_in[15];
  const float* bn2m = (const float*)d_in[16]; const float* bn2v = (const float*)d_in[17];
  const float* l0W = (const float*)d_in[18]; const float* l0b = (const float*)d_in[19];
  const float* l1W = (const float*)d_in[20]; const float* l1b = (const float*)d_in[21];
  const float* l2W = (const float*)d_in[22]; const float* l2b = (const float*)d_in[23];
  float* out = (float*)d_out;

  char* p = (char*)d_ws;
  auto alloc = [&](size_t bytes) { char* q = p; p += (bytes + 255) & ~(size_t)255; return q; };
  float* h0    = (float*)alloc((size_t)N0c * 128 * 4);   // layer1 reuses as g1
  float* h1    = (float*)alloc((size_t)N0c * 128 * 4);   // layer1 reuses as h2
  float* xp1   = (float*)alloc((size_t)N1c * 128 * 4);
  float* dinv  = (float*)alloc((size_t)N0c * 4);
  float* dinv2 = (float*)alloc((size_t)N1c * 4);
  int*   rp    = (int*)alloc((size_t)Bg * (NPG + 1) * 4);
  int*   rp2   = (int*)alloc((size_t)Bg * (K1c + 1) * 4);
  int2*  e2    = (int2*)alloc((size_t)Etot * 8);
  float* spre  = (float*)alloc((size_t)N0c * 4);
  float* sv    = (float*)alloc((size_t)N0c * 4);
  int*   perm  = (int*)alloc((size_t)N1c * 4);
  unsigned short* pk = (unsigned short*)alloc((size_t)65536 * 2);
  float* pooled= (float*)alloc((size_t)3 * Bg * 128 * 4);

  dim3 b256(256), b512(512), b128(128);

  // ---------------- layer 0 ----------------
  k_packW<<<128, b256, 0, stream>>>(c1W, c2W, pk);
  k_prep0<<<Bg, b512, 0, stream>>>(src0, dst0, x, dinv, rp, e2, pooled);
  k_gemm3<<<N0c / 64, b256, 0, stream>>>(x, pk, h0);
  k_agg3<NPG, 64><<<128 * 64, b256, 0, stream>>>(h0, dinv, c1b, rp, e2, s1W, h1, spre);
  k_score2<NPG><<<(N0c + 255) / 256, b256, 0, stream>>>(spre, dinv, s1b, rp, e2, sv, N0c);
  k_repool<NPG, K1c><<<Bg, b512, 0, stream>>>(sv, src0, dst0, perm, dinv2, rp2, e2);
  k_poolbn<K1c, 8, true><<<Bg * 8, b128, 0, stream>>>(h1, sv, perm, bn1g, bn1b, bn1m, bn1v,
                                                      xp1, pooled + Bg * 128);

  // ---------------- layer 1 ----------------
  float* g1 = h0;   // h0 dead after layer-0 agg
  float* h2 = h1;   // h1 dead after poolbn
  k_gemm3<<<N1c / 64, b256, 0, stream>>>(xp1, pk + 32768, g1);
  k_agg3<K1c, 52><<<128 * 52, b256, 0, stream>>>(g1, dinv2, c2b, rp2, e2, s2W, h2, spre);
  k_score2<K1c><<<(N1c + 255) / 256, b256, 0, stream>>>(spre, dinv2, s2b, rp2, e2, sv, N1c);
  k_topk<K1c, K2c><<<Bg, b256, 0, stream>>>(sv, perm);
  k_poolbn<K2c, 8, false><<<Bg * 8, b128, 0, stream>>>(h2, sv, perm, bn2g, bn2b, bn2m, bn2v,
                                                       nullptr, pooled + 2 * Bg * 128);

  // ---------------- readout ----------------
  k_final<<<(Bg * DOUTc + 255) / 256, b256, 0, stream>>>(pooled, l0W, l0b, l1W, l1b, l2W, l2b, out);
}

// Round 9
// 339.650 us; speedup vs baseline: 1.2272x; 1.1339x over previous
//
#include <hip/hip_runtime.h>

#define Bg   128
#define NPG  512
#define EPGc 8192
#define Etot (Bg*EPGc)
#define DOUTc 10
#define K1c  410
#define K2c  328
#define N0c  (Bg*NPG)
#define N1c  (Bg*K1c)
#define N2c  (Bg*K2c)
#define EPSc 1e-5f

typedef __attribute__((ext_vector_type(8))) short s8v;   // 8 bf16 (4 VGPRs)
typedef __attribute__((ext_vector_type(4))) float f4v;   // mfma acc

static __device__ __forceinline__ unsigned short bf_rne(float x) {
  unsigned u = __float_as_uint(x);
  u += 0x7FFFu + ((u >> 16) & 1u);       // round-to-nearest-even
  return (unsigned short)(u >> 16);
}
static __device__ __forceinline__ float bf_f(unsigned short h) {
  return __uint_as_float(((unsigned)h) << 16);
}

// ---------------- layer-0 graph prep (+ fused W-packing) ----------------
// block g: LDS in-degree count -> dinv -> scan -> packed CSR scatter; zero pooled;
// threads<256 also pack 256 W entries into MFMA B-frag bf16 hi/lo layout.
static __global__ __launch_bounds__(512) void k_prep0(const int* __restrict__ src,
                                                      const int* __restrict__ dst,
                                                      const float* __restrict__ W1,
                                                      const float* __restrict__ W2,
                                                      unsigned short* __restrict__ pk,
                                                      float* __restrict__ dinv,
                                                      int* __restrict__ rp,
                                                      int2* __restrict__ e2,
                                                      float* __restrict__ pooled) {
  __shared__ int    cnt[NPG];
  __shared__ float  sdv[NPG];
  __shared__ int    srp[NPG];
  __shared__ int    sbuf[512];
  int g = blockIdx.x, tid = threadIdx.x;
  cnt[tid] = 0;
  if (tid < 128) {                       // zero all pooled slices (atomic targets)
    pooled[g * 128 + tid] = 0.f;
    pooled[Bg * 128 + g * 128 + tid] = 0.f;
    pooled[2 * Bg * 128 + g * 128 + tid] = 0.f;
  }
  if (tid < 256) {                       // fused packW: i in [0,32768)
    int i = g * 256 + tid;
    const float* W = (i < 16384) ? W1 : W2;
    unsigned short* d = pk + ((i < 16384) ? 0 : 32768);
    int ii = i & 16383;
    int grp = ii >> 9, lane = (ii >> 3) & 63, j = ii & 7;
    int kk = grp >> 3, t = grp & 7;
    int k = kk * 32 + (lane >> 4) * 8 + j;
    int n = t * 16 + (lane & 15);
    float w = W[k * 128 + n];
    unsigned short hi = bf_rne(w);
    d[ii] = hi;
    d[16384 + ii] = bf_rne(w - bf_f(hi));
  }
  __syncthreads();
  const int* sp = src + (size_t)g * EPGc;
  const int* dp = dst + (size_t)g * EPGc;
  for (int e = tid; e < EPGc; e += 512) atomicAdd(&cnt[dp[e] - g * NPG], 1);
  __syncthreads();
  int c = cnt[tid];
  float dv = 1.0f / sqrtf(1.0f + (float)c);
  sdv[tid] = dv;
  dinv[g * NPG + tid] = dv;
  sbuf[tid] = c;
  __syncthreads();
  for (int off = 1; off < 512; off <<= 1) {
    int t = (tid >= off) ? sbuf[tid - off] : 0;
    __syncthreads();
    sbuf[tid] += t;
    __syncthreads();
  }
  srp[tid] = sbuf[tid] - c;
  rp[g * (NPG + 1) + tid] = sbuf[tid] - c;
  if (tid == 511) rp[g * (NPG + 1) + NPG] = sbuf[511];
  cnt[tid] = 0;
  __syncthreads();
  for (int e = tid; e < EPGc; e += 512) {
    int s = sp[e], d = dp[e];
    int dl = d - g * NPG;
    int pos = srp[dl] + atomicAdd(&cnt[dl], 1);
    e2[(size_t)g * EPGc + pos] =
        make_int2(s, __float_as_int(sdv[s - g * NPG] * sdv[dl]));
  }
}

// grid-parallel x graph-sum (round-9: un-fused from prep0 — 128 blocks couldn't
// saturate HBM, prep0 was 49us latency-bound). Bg*16 blocks, atomic combine.
static __global__ __launch_bounds__(128) void k_xsum(const float* __restrict__ x,
                                                     float* __restrict__ pooled0) {
  int g = blockIdx.x >> 4, c = blockIdx.x & 15;
  int f = threadIdx.x;
  float acc = 0.f;
  const float* p = x + ((size_t)g * NPG + c * 32) * 128 + f;
  for (int i = 0; i < 32; ++i, p += 128) acc += *p;
  atomicAdd(&pooled0[g * 128 + f], acc);
}

// ---------------- MFMA GEMM: Y[M x 128] = X[M x 128] @ W (bf16 hi/lo split) ----
static __global__ __launch_bounds__(256) void k_gemm3(const float* __restrict__ X,
                                                      const unsigned short* __restrict__ pk,
                                                      float* __restrict__ Y) {
  __shared__ unsigned short wl[32768];   // 64 KB: hi[16384] + lo[16384]
  int tid = threadIdx.x;
  for (int i = tid; i < 4096; i += 256) ((int4*)wl)[i] = ((const int4*)pk)[i];
  int wv = tid >> 6, lane = tid & 63;
  int q = lane >> 4, m16 = lane & 15;
  size_t row = (size_t)blockIdx.x * 64 + wv * 16 + m16;
  s8v ahi[4], alo[4];
#pragma unroll
  for (int kk = 0; kk < 4; ++kk) {
    const float* xr = X + row * 128 + kk * 32 + q * 8;
    float4 a0 = *(const float4*)xr;
    float4 a1 = *(const float4*)(xr + 4);
    float av[8] = {a0.x, a0.y, a0.z, a0.w, a1.x, a1.y, a1.z, a1.w};
    union { unsigned short u[8]; s8v v; } H, L;
#pragma unroll
    for (int j = 0; j < 8; ++j) {
      unsigned short h = bf_rne(av[j]);
      H.u[j] = h;
      L.u[j] = bf_rne(av[j] - bf_f(h));
    }
    ahi[kk] = H.v; alo[kk] = L.v;
  }
  __syncthreads();
  int orow0 = blockIdx.x * 64 + wv * 16 + q * 4;
#pragma unroll
  for (int t = 0; t < 8; ++t) {
    f4v acc = {0.f, 0.f, 0.f, 0.f};
#pragma unroll
    for (int kk = 0; kk < 4; ++kk) {
      s8v bhi = *(const s8v*)&wl[(kk * 8 + t) * 512 + lane * 8];
      s8v blo = *(const s8v*)&wl[16384 + (kk * 8 + t) * 512 + lane * 8];
      acc = __builtin_amdgcn_mfma_f32_16x16x32_bf16(ahi[kk], bhi, acc, 0, 0, 0);
      acc = __builtin_amdgcn_mfma_f32_16x16x32_bf16(alo[kk], bhi, acc, 0, 0, 0);
      acc = __builtin_amdgcn_mfma_f32_16x16x32_bf16(ahi[kk], blo, acc, 0, 0, 0);
    }
#pragma unroll
    for (int r = 0; r < 4; ++r)
      Y[(size_t)(orow0 + r) * 128 + t * 16 + m16] = acc[r];
  }
}

// GCN aggregation: round-6 x4 body (round-8's x8 raised VGPR 24->44, occ 62->41%,
// 42.5->47.7us — reverted). L2 gather + fused score GEMV.
template <int NPER, int RG>
static __global__ __launch_bounds__(256) void k_agg3(const float* __restrict__ h0,
                                                     const float* __restrict__ dinv,
                                                     const float* __restrict__ bias,
                                                     const int* __restrict__ rp,
                                                     const int2* __restrict__ e2,
                                                     const float* __restrict__ sw,
                                                     float* __restrict__ h1,
                                                     float* __restrict__ spre) {
  int tid = threadIdx.x;
  int hw = tid >> 5, l = tid & 31;
  int b = blockIdx.x;
  int xcd = b & 7, slot = b >> 3;
  int g = xcd * 16 + (slot & 15);
  int rowgrp = slot >> 4;
  int li = rowgrp * 8 + hw;
  if (li >= NPER) return;
  int j = g * NPER + li;
  const int* rpg = rp + g * (NPER + 1);
  int start = rpg[li], end = rpg[li + 1];
  const int2* ep = e2 + (size_t)g * EPGc;
  float di = dinv[j];
  float sc = di * di;
  float4 acc = *(const float4*)&h0[(size_t)j * 128 + l * 4];
  float4 bb = ((const float4*)bias)[l];
  acc.x = acc.x * sc + bb.x; acc.y = acc.y * sc + bb.y;
  acc.z = acc.z * sc + bb.z; acc.w = acc.w * sc + bb.w;
  int e = start;
  for (; e + 4 <= end; e += 4) {
    int2 p0 = ep[e], p1 = ep[e + 1], p2 = ep[e + 2], p3 = ep[e + 3];
    float4 v0 = *(const float4*)&h0[(size_t)p0.x * 128 + l * 4];
    float4 v1 = *(const float4*)&h0[(size_t)p1.x * 128 + l * 4];
    float4 v2 = *(const float4*)&h0[(size_t)p2.x * 128 + l * 4];
    float4 v3 = *(const float4*)&h0[(size_t)p3.x * 128 + l * 4];
    float c0 = __int_as_float(p0.y), c1 = __int_as_float(p1.y);
    float c2 = __int_as_float(p2.y), c3 = __int_as_float(p3.y);
    acc.x += v0.x * c0 + v1.x * c1 + v2.x * c2 + v3.x * c3;
    acc.y += v0.y * c0 + v1.y * c1 + v2.y * c2 + v3.y * c3;
    acc.z += v0.z * c0 + v1.z * c1 + v2.z * c2 + v3.z * c3;
    acc.w += v0.w * c0 + v1.w * c1 + v2.w * c2 + v3.w * c3;
  }
  for (; e < end; ++e) {
    int2 pp = ep[e];
    float c = __int_as_float(pp.y);
    float4 v = *(const float4*)&h0[(size_t)pp.x * 128 + l * 4];
    acc.x += v.x * c; acc.y += v.y * c; acc.z += v.z * c; acc.w += v.w * c;
  }
  ((float4*)&h1[(size_t)j * 128])[l] = acc;
  float4 w4 = ((const float4*)sw)[l];
  float pr = acc.x * w4.x + acc.y * w4.y + acc.z * w4.z + acc.w * w4.w;
#pragma unroll
  for (int off = 16; off; off >>= 1) pr += __shfl_xor(pr, off, 64);
  if (l == 0) spre[j] = pr;
}

// s[j] = spre[j]*dinv^2 + b + sum_e cval*spre[col]  (x8 unrolled scalar gathers)
template <int NPER>
static __global__ void k_score2(const float* __restrict__ spre, const float* __restrict__ dinv,
                                const float* __restrict__ bptr, const int* __restrict__ rp,
                                const int2* __restrict__ e2, float* __restrict__ s, int n) {
  int j = blockIdx.x * 256 + threadIdx.x;
  if (j >= n) return;
  int g = j / NPER, li = j - g * NPER;
  const int* rpg = rp + g * (NPER + 1);
  int start = rpg[li], end = rpg[li + 1];
  const int2* ep = e2 + (size_t)g * EPGc;
  float di = dinv[j];
  float acc = spre[j] * di * di + bptr[0];
  int e = start;
  for (; e + 8 <= end; e += 8) {
    int2 p[8];
#pragma unroll
    for (int q = 0; q < 8; ++q) p[q] = ep[e + q];
    float a[8];
#pragma unroll
    for (int q = 0; q < 8; ++q) a[q] = spre[p[q].x];
#pragma unroll
    for (int q = 0; q < 8; ++q) acc += a[q] * __int_as_float(p[q].y);
  }
  for (; e + 4 <= end; e += 4) {
    int2 p0 = ep[e], p1 = ep[e + 1], p2 = ep[e + 2], p3 = ep[e + 3];
    float a0 = spre[p0.x], a1 = spre[p1.x], a2 = spre[p2.x], a3 = spre[p3.x];
    acc += a0 * __int_as_float(p0.y) + a1 * __int_as_float(p1.y) +
           a2 * __int_as_float(p2.y) + a3 * __int_as_float(p3.y);
  }
  for (; e < end; ++e) { int2 pp = ep[e]; acc += spre[pp.x] * __int_as_float(pp.y); }
  s[j] = acc;
}

// topk + remap + edge filter + CSR rebuild, per graph
template <int NPER, int K>
static __global__ __launch_bounds__(512) void k_repool(const float* __restrict__ sv,
                                                       const int* __restrict__ src,
                                                       const int* __restrict__ dst,
                                                       int* __restrict__ perm,
                                                       float* __restrict__ dinv2,
                                                       int* __restrict__ rp2,
                                                       int2* __restrict__ e2) {
  __shared__ float sc[512];
  __shared__ int   sidx[512];
  __shared__ short rmp[NPER];
  __shared__ int   cnt[K];
  __shared__ float sdv[K];
  __shared__ int   srp[K];
  __shared__ int   sbuf[512];
  int g = blockIdx.x, tid = threadIdx.x;
  sc[tid] = (tid < NPER) ? sv[g * NPER + tid] : -3.402823466e38f;
  sidx[tid] = tid;
  if (tid < NPER) rmp[tid] = -1;
  __syncthreads();
  for (int kk = 2; kk <= 512; kk <<= 1) {
    for (int j = kk >> 1; j > 0; j >>= 1) {
      int i = tid, p = i ^ j;
      if (p > i) {
        bool up = ((i & kk) == 0);
        float si = sc[i], sp2 = sc[p];
        if (up ? (si < sp2) : (si > sp2)) {
          sc[i] = sp2; sc[p] = si;
          int t = sidx[i]; sidx[i] = sidx[p]; sidx[p] = t;
        }
      }
      __syncthreads();
    }
  }
  if (tid < K) {
    perm[g * K + tid] = g * NPER + sidx[tid];
    rmp[sidx[tid]] = (short)tid;
    cnt[tid] = 0;
  }
  __syncthreads();
  const int* sp = src + (size_t)g * EPGc;
  const int* dp = dst + (size_t)g * EPGc;
  for (int e = tid; e < EPGc; e += 512) {
    int s = rmp[sp[e] - g * NPER];
    int d = rmp[dp[e] - g * NPER];
    if ((s | d) >= 0) atomicAdd(&cnt[d], 1);
  }
  __syncthreads();
  int c = (tid < K) ? cnt[tid] : 0;
  if (tid < K) {
    float dv = 1.0f / sqrtf(1.0f + (float)c);
    sdv[tid] = dv;
    dinv2[g * K + tid] = dv;
  }
  sbuf[tid] = c;
  __syncthreads();
  for (int off = 1; off < 512; off <<= 1) {
    int t = (tid >= off) ? sbuf[tid - off] : 0;
    __syncthreads();
    sbuf[tid] += t;
    __syncthreads();
  }
  if (tid < K) { srp[tid] = sbuf[tid] - c; rp2[g * (K + 1) + tid] = sbuf[tid] - c; cnt[tid] = 0; }
  if (tid == 511) rp2[g * (K + 1) + K] = sbuf[511];
  __syncthreads();
  for (int e = tid; e < EPGc; e += 512) {
    int s = rmp[sp[e] - g * NPER];
    int d = rmp[dp[e] - g * NPER];
    if ((s | d) >= 0) {
      int pos = srp[d] + atomicAdd(&cnt[d], 1);
      e2[(size_t)g * EPGc + pos] = make_int2(g * K + s, __float_as_int(sdv[s] * sdv[d]));
    }
  }
}

// plain per-graph top-K (layer 2 needs no edge rebuild)
template <int NPER, int K>
static __global__ __launch_bounds__(256) void k_topk(const float* __restrict__ s,
                                                     int* __restrict__ perm) {
  __shared__ float sc[512];
  __shared__ int   idx[512];
  int g = blockIdx.x, tid = threadIdx.x;
  for (int i = tid; i < 512; i += 256) {
    if (i < NPER) { sc[i] = s[g * NPER + i]; idx[i] = i; }
    else          { sc[i] = -3.402823466e38f; idx[i] = 0; }
  }
  __syncthreads();
  for (int kk = 2; kk <= 512; kk <<= 1) {
    for (int j = kk >> 1; j > 0; j >>= 1) {
      for (int base = 0; base < 512; base += 256) {
        int i = base + tid;
        int p = i ^ j;
        if (p > i) {
          bool up = ((i & kk) == 0);
          float si = sc[i], sp = sc[p];
          if (up ? (si < sp) : (si > sp)) {
            sc[i] = sp; sc[p] = si;
            int t = idx[i]; idx[i] = idx[p]; idx[p] = t;
          }
        }
      }
      __syncthreads();
    }
  }
  for (int r = tid; r < K; r += 256) perm[g * K + r] = g * NPER + idx[r];
}

// xp[j] = relu(bn(h[perm[j]]*tanh(s[perm[j]]))), fused graph-sum via one atomic
// per (block, feature). CH=16 -> 2048 blocks for latency hiding.
template <int NPER, int CH, bool WXP>
static __global__ __launch_bounds__(128) void k_poolbn(const float* __restrict__ h,
                                                       const float* __restrict__ s,
                                                       const int* __restrict__ perm,
                                                       const float* __restrict__ gg,
                                                       const float* __restrict__ bb,
                                                       const float* __restrict__ mm,
                                                       const float* __restrict__ vv,
                                                       float* __restrict__ xp,
                                                       float* __restrict__ pooledseg) {
  int g = blockIdx.x / CH, cidx = blockIdx.x - g * CH;
  int f = threadIdx.x;
  const int rows = (NPER + CH - 1) / CH;
  int r0 = cidx * rows, r1 = min(NPER, r0 + rows);
  if (r0 >= r1) return;
  float G = gg[f], Bb = bb[f], Mm = mm[f];
  float inv = 1.0f / sqrtf(vv[f] + EPSc);
  float acc = 0.f;
  for (int r = r0; r < r1; ++r) {
    int j = g * NPER + r;
    int old = perm[j];
    float t = tanhf(s[old]);
    float val = h[(size_t)old * 128 + f] * t;
    float o = fmaxf(G * (val - Mm) * inv + Bb, 0.f);
    if (WXP) xp[(size_t)j * 128 + f] = o;
    acc += o;
  }
  atomicAdd(&pooledseg[g * 128 + f], acc);
}

static __global__ void k_final(const float* __restrict__ pooled,
                               const float* __restrict__ w0, const float* __restrict__ b0,
                               const float* __restrict__ w1, const float* __restrict__ b1,
                               const float* __restrict__ w2, const float* __restrict__ b2,
                               float* __restrict__ out) {
  int t = blockIdx.x * 256 + threadIdx.x;
  if (t >= Bg * DOUTc) return;
  int g = t / DOUTc, o = t - g * DOUTc;
  const float* p0 = pooled + g * 128;
  const float* p1 = pooled + Bg * 128 + g * 128;
  const float* p2 = pooled + 2 * Bg * 128 + g * 128;
  float acc = b0[o] + b1[o] + b2[o];
  for (int k = 0; k < 128; ++k)
    acc += p0[k] * w0[o * 128 + k] + p1[k] * w1[o * 128 + k] + p2[k] * w2[o * 128 + k];
  out[t] = acc;
}

extern "C" void kernel_launch(void* const* d_in, const int* in_sizes, int n_in,
                              void* d_out, int out_size, void* d_ws, size_t ws_size,
                              hipStream_t stream) {
  (void)in_sizes; (void)n_in; (void)out_size; (void)ws_size;
  const float* x    = (const float*)d_in[0];
  const int*   ei   = (const int*)d_in[1];
  const int*   src0 = ei;
  const int*   dst0 = ei + Etot;
  const float* c1W = (const float*)d_in[2];  const float* c1b = (const float*)d_in[3];
  const float* c2W = (const float*)d_in[4];  const float* c2b = (const float*)d_in[5];
  const float* s1W = (const float*)d_in[6];  const float* s1b = (const float*)d_in[7];
  const float* s2W = (const float*)d_in[8];  const float* s2b = (const float*)d_in[9];
  const float* bn1g = (const float*)d_in[10]; const float* bn1b = (const float*)d_in[11];
  const float* bn1m = (const float*)d_in[12]; const float* bn1v = (const float*)d_in[13];
  const float* bn2g = (const float*)d_in[14]; const float* bn2b = (const float*)d_in[15];
  const float* bn2m = (const float*)d_in[16]; const float* bn2v = (const float*)d_in[17];
  const float* l0W = (const float*)d_in[18]; const float* l0b = (const float*)d_in[19];
  const float* l1W = (const float*)d_in[20]; const float* l1b = (const float*)d_in[21];
  const float* l2W = (const float*)d_in[22]; const float* l2b = (const float*)d_in[23];
  float* out = (float*)d_out;

  char* p = (char*)d_ws;
  auto alloc = [&](size_t bytes) { char* q = p; p += (bytes + 255) & ~(size_t)255; return q; };
  float* h0    = (float*)alloc((size_t)N0c * 128 * 4);   // layer1 reuses as g1
  float* h1    = (float*)alloc((size_t)N0c * 128 * 4);   // layer1 reuses as h2
  float* xp1   = (float*)alloc((size_t)N1c * 128 * 4);
  float* dinv  = (float*)alloc((size_t)N0c * 4);
  float* dinv2 = (float*)alloc((size_t)N1c * 4);
  int*   rp    = (int*)alloc((size_t)Bg * (NPG + 1) * 4);
  int*   rp2   = (int*)alloc((size_t)Bg * (K1c + 1) * 4);
  int2*  e2    = (int2*)alloc((size_t)Etot * 8);
  float* spre  = (float*)alloc((size_t)N0c * 4);
  float* sv    = (float*)alloc((size_t)N0c * 4);
  int*   perm  = (int*)alloc((size_t)N1c * 4);
  unsigned short* pk = (unsigned short*)alloc((size_t)65536 * 2);
  float* pooled= (float*)alloc((size_t)3 * Bg * 128 * 4);

  dim3 b256(256), b512(512), b128(128);

  // ---------------- layer 0 ----------------
  k_prep0<<<Bg, b512, 0, stream>>>(src0, dst0, c1W, c2W, pk, dinv, rp, e2, pooled);
  k_xsum<<<Bg * 16, b128, 0, stream>>>(x, pooled);
  k_gemm3<<<N0c / 64, b256, 0, stream>>>(x, pk, h0);
  k_agg3<NPG, 64><<<128 * 64, b256, 0, stream>>>(h0, dinv, c1b, rp, e2, s1W, h1, spre);
  k_score2<NPG><<<(N0c + 255) / 256, b256, 0, stream>>>(spre, dinv, s1b, rp, e2, sv, N0c);
  k_repool<NPG, K1c><<<Bg, b512, 0, stream>>>(sv, src0, dst0, perm, dinv2, rp2, e2);
  k_poolbn<K1c, 16, true><<<Bg * 16, b128, 0, stream>>>(h1, sv, perm, bn1g, bn1b, bn1m, bn1v,
                                                        xp1, pooled + Bg * 128);

  // ---------------- layer 1 ----------------
  float* g1 = h0;   // h0 dead after layer-0 agg
  float* h2 = h1;   // h1 dead after poolbn
  k_gemm3<<<N1c / 64, b256, 0, stream>>>(xp1, pk + 32768, g1);
  k_agg3<K1c, 52><<<128 * 52, b256, 0, stream>>>(g1, dinv2, c2b, rp2, e2, s2W, h2, spre);
  k_score2<K1c><<<(N1c + 255) / 256, b256, 0, stream>>>(spre, dinv2, s2b, rp2, e2, sv, N1c);
  k_topk<K1c, K2c><<<Bg, b256, 0, stream>>>(sv, perm);
  k_poolbn<K2c, 16, false><<<Bg * 16, b128, 0, stream>>>(h2, sv, perm, bn2g, bn2b, bn2m, bn2v,
                                                         nullptr, pooled + 2 * Bg * 128);

  // ---------------- readout ----------------
  k_final<<<(Bg * DOUTc + 255) / 256, b256, 0, stream>>>(pooled, l0W, l0b, l1W, l1b, l2W, l2b, out);
}

// Round 10
// 334.801 us; speedup vs baseline: 1.2450x; 1.0145x over previous
//
#include <hip/hip_runtime.h>

#define Bg   128
#define NPG  512
#define EPGc 8192
#define Etot (Bg*EPGc)
#define DOUTc 10
#define K1c  410
#define K2c  328
#define N0c  (Bg*NPG)
#define N1c  (Bg*K1c)
#define N2c  (Bg*K2c)
#define EPSc 1e-5f

typedef __attribute__((ext_vector_type(8))) short s8v;   // 8 bf16 (4 VGPRs)
typedef __attribute__((ext_vector_type(4))) float f4v;   // mfma acc

static __device__ __forceinline__ unsigned short bf_rne(float x) {
  unsigned u = __float_as_uint(x);
  u += 0x7FFFu + ((u >> 16) & 1u);       // round-to-nearest-even
  return (unsigned short)(u >> 16);
}
static __device__ __forceinline__ float bf_f(unsigned short h) {
  return __uint_as_float(((unsigned)h) << 16);
}

// ---------------- layer-0 graph prep (+ fused W-packing) ----------------
static __global__ __launch_bounds__(512) void k_prep0(const int* __restrict__ src,
                                                      const int* __restrict__ dst,
                                                      const float* __restrict__ W1,
                                                      const float* __restrict__ W2,
                                                      unsigned short* __restrict__ pk,
                                                      float* __restrict__ dinv,
                                                      int* __restrict__ rp,
                                                      int2* __restrict__ e2,
                                                      float* __restrict__ pooled) {
  __shared__ int    cnt[NPG];
  __shared__ float  sdv[NPG];
  __shared__ int    srp[NPG];
  __shared__ int    sbuf[512];
  int g = blockIdx.x, tid = threadIdx.x;
  cnt[tid] = 0;
  if (tid < 128) {                       // zero all pooled slices (atomic targets)
    pooled[g * 128 + tid] = 0.f;
    pooled[Bg * 128 + g * 128 + tid] = 0.f;
    pooled[2 * Bg * 128 + g * 128 + tid] = 0.f;
  }
  if (tid < 256) {                       // fused packW: i in [0,32768)
    int i = g * 256 + tid;
    const float* W = (i < 16384) ? W1 : W2;
    unsigned short* d = pk + ((i < 16384) ? 0 : 32768);
    int ii = i & 16383;
    int grp = ii >> 9, lane = (ii >> 3) & 63, j = ii & 7;
    int kk = grp >> 3, t = grp & 7;
    int k = kk * 32 + (lane >> 4) * 8 + j;
    int n = t * 16 + (lane & 15);
    float w = W[k * 128 + n];
    unsigned short hi = bf_rne(w);
    d[ii] = hi;
    d[16384 + ii] = bf_rne(w - bf_f(hi));
  }
  __syncthreads();
  const int* sp = src + (size_t)g * EPGc;
  const int* dp = dst + (size_t)g * EPGc;
  for (int e = tid; e < EPGc; e += 512) atomicAdd(&cnt[dp[e] - g * NPG], 1);
  __syncthreads();
  int c = cnt[tid];
  float dv = 1.0f / sqrtf(1.0f + (float)c);
  sdv[tid] = dv;
  dinv[g * NPG + tid] = dv;
  sbuf[tid] = c;
  __syncthreads();
  for (int off = 1; off < 512; off <<= 1) {
    int t = (tid >= off) ? sbuf[tid - off] : 0;
    __syncthreads();
    sbuf[tid] += t;
    __syncthreads();
  }
  srp[tid] = sbuf[tid] - c;
  rp[g * (NPG + 1) + tid] = sbuf[tid] - c;
  if (tid == 511) rp[g * (NPG + 1) + NPG] = sbuf[511];
  cnt[tid] = 0;
  __syncthreads();
  for (int e = tid; e < EPGc; e += 512) {
    int s = sp[e], d = dp[e];
    int dl = d - g * NPG;
    int pos = srp[dl] + atomicAdd(&cnt[dl], 1);
    e2[(size_t)g * EPGc + pos] =
        make_int2(s, __float_as_int(sdv[s - g * NPG] * sdv[dl]));
  }
}

// ---------------- MFMA GEMM (+optional fused x graph-sum) ----------------
// p0 != nullptr (layer 0): each thread shuffle-reduces its A values over the 16
// m16 row-lanes, m16==0 lanes atomicAdd to pooled0 -> kills the k_xsum dispatch.
static __global__ __launch_bounds__(256) void k_gemm3(const float* __restrict__ X,
                                                      const unsigned short* __restrict__ pk,
                                                      float* __restrict__ Y,
                                                      float* __restrict__ p0) {
  __shared__ unsigned short wl[32768];   // 64 KB: hi[16384] + lo[16384]
  int tid = threadIdx.x;
  for (int i = tid; i < 4096; i += 256) ((int4*)wl)[i] = ((const int4*)pk)[i];
  int wv = tid >> 6, lane = tid & 63;
  int q = lane >> 4, m16 = lane & 15;
  size_t row = (size_t)blockIdx.x * 64 + wv * 16 + m16;
  float* pg = p0 ? (p0 + (size_t)(blockIdx.x >> 3) * 128) : nullptr;
  s8v ahi[4], alo[4];
#pragma unroll
  for (int kk = 0; kk < 4; ++kk) {
    const float* xr = X + row * 128 + kk * 32 + q * 8;
    float4 a0 = *(const float4*)xr;
    float4 a1 = *(const float4*)(xr + 4);
    float av[8] = {a0.x, a0.y, a0.z, a0.w, a1.x, a1.y, a1.z, a1.w};
    if (pg) {
#pragma unroll
      for (int j = 0; j < 8; ++j) {
        float v = av[j];
        v += __shfl_xor(v, 1, 64); v += __shfl_xor(v, 2, 64);
        v += __shfl_xor(v, 4, 64); v += __shfl_xor(v, 8, 64);
        if (m16 == 0) atomicAdd(&pg[kk * 32 + q * 8 + j], v);
      }
    }
    union { unsigned short u[8]; s8v v; } H, L;
#pragma unroll
    for (int j = 0; j < 8; ++j) {
      unsigned short h = bf_rne(av[j]);
      H.u[j] = h;
      L.u[j] = bf_rne(av[j] - bf_f(h));
    }
    ahi[kk] = H.v; alo[kk] = L.v;
  }
  __syncthreads();
  int orow0 = blockIdx.x * 64 + wv * 16 + q * 4;
#pragma unroll
  for (int t = 0; t < 8; ++t) {
    f4v acc = {0.f, 0.f, 0.f, 0.f};
#pragma unroll
    for (int kk = 0; kk < 4; ++kk) {
      s8v bhi = *(const s8v*)&wl[(kk * 8 + t) * 512 + lane * 8];
      s8v blo = *(const s8v*)&wl[16384 + (kk * 8 + t) * 512 + lane * 8];
      acc = __builtin_amdgcn_mfma_f32_16x16x32_bf16(ahi[kk], bhi, acc, 0, 0, 0);
      acc = __builtin_amdgcn_mfma_f32_16x16x32_bf16(alo[kk], bhi, acc, 0, 0, 0);
      acc = __builtin_amdgcn_mfma_f32_16x16x32_bf16(ahi[kk], blo, acc, 0, 0, 0);
    }
#pragma unroll
    for (int r = 0; r < 4; ++r)
      Y[(size_t)(orow0 + r) * 128 + t * 16 + m16] = acc[r];
  }
}

// GCN aggregation: x4 L2 gather + fused score GEMV (unchanged — at its mixed-L2
// roofline: 612 MB @ 14.2 TB/s, 97% L2 hit).
template <int NPER, int RG>
static __global__ __launch_bounds__(256) void k_agg3(const float* __restrict__ h0,
                                                     const float* __restrict__ dinv,
                                                     const float* __restrict__ bias,
                                                     const int* __restrict__ rp,
                                                     const int2* __restrict__ e2,
                                                     const float* __restrict__ sw,
                                                     float* __restrict__ h1,
                                                     float* __restrict__ spre) {
  int tid = threadIdx.x;
  int hw = tid >> 5, l = tid & 31;
  int b = blockIdx.x;
  int xcd = b & 7, slot = b >> 3;
  int g = xcd * 16 + (slot & 15);
  int rowgrp = slot >> 4;
  int li = rowgrp * 8 + hw;
  if (li >= NPER) return;
  int j = g * NPER + li;
  const int* rpg = rp + g * (NPER + 1);
  int start = rpg[li], end = rpg[li + 1];
  const int2* ep = e2 + (size_t)g * EPGc;
  float di = dinv[j];
  float sc = di * di;
  float4 acc = *(const float4*)&h0[(size_t)j * 128 + l * 4];
  float4 bb = ((const float4*)bias)[l];
  acc.x = acc.x * sc + bb.x; acc.y = acc.y * sc + bb.y;
  acc.z = acc.z * sc + bb.z; acc.w = acc.w * sc + bb.w;
  int e = start;
  for (; e + 4 <= end; e += 4) {
    int2 p0 = ep[e], p1 = ep[e + 1], p2 = ep[e + 2], p3 = ep[e + 3];
    float4 v0 = *(const float4*)&h0[(size_t)p0.x * 128 + l * 4];
    float4 v1 = *(const float4*)&h0[(size_t)p1.x * 128 + l * 4];
    float4 v2 = *(const float4*)&h0[(size_t)p2.x * 128 + l * 4];
    float4 v3 = *(const float4*)&h0[(size_t)p3.x * 128 + l * 4];
    float c0 = __int_as_float(p0.y), c1 = __int_as_float(p1.y);
    float c2 = __int_as_float(p2.y), c3 = __int_as_float(p3.y);
    acc.x += v0.x * c0 + v1.x * c1 + v2.x * c2 + v3.x * c3;
    acc.y += v0.y * c0 + v1.y * c1 + v2.y * c2 + v3.y * c3;
    acc.z += v0.z * c0 + v1.z * c1 + v2.z * c2 + v3.z * c3;
    acc.w += v0.w * c0 + v1.w * c1 + v2.w * c2 + v3.w * c3;
  }
  for (; e < end; ++e) {
    int2 pp = ep[e];
    float c = __int_as_float(pp.y);
    float4 v = *(const float4*)&h0[(size_t)pp.x * 128 + l * 4];
    acc.x += v.x * c; acc.y += v.y * c; acc.z += v.z * c; acc.w += v.w * c;
  }
  ((float4*)&h1[(size_t)j * 128])[l] = acc;
  float4 w4 = ((const float4*)sw)[l];
  float pr = acc.x * w4.x + acc.y * w4.y + acc.z * w4.z + acc.w * w4.w;
#pragma unroll
  for (int off = 16; off; off >>= 1) pr += __shfl_xor(pr, off, 64);
  if (l == 0) spre[j] = pr;
}

// ---------------- repool: score + topk + remap + edge filter + CSR rebuild ----
// Round-10: score folded in (spre LDS-staged, ~16 LDS gathers/thread) — kills the
// score2 dispatch. Also stores tanh(score) per selected node so poolbn needs no
// s-gather/tanhf. (Round-7 lesson: keep the 21 MB poolbn gather OUT of here.)
template <int NPER, int K>
static __global__ __launch_bounds__(512) void k_repool(const float* __restrict__ spre,
                                                       const float* __restrict__ dinv,
                                                       const float* __restrict__ sb,
                                                       const int* __restrict__ rp,
                                                       const int* __restrict__ src,
                                                       const int* __restrict__ dst,
                                                       int* __restrict__ perm,
                                                       float* __restrict__ tsel,
                                                       float* __restrict__ dinv2,
                                                       int* __restrict__ rp2,
                                                       int2* __restrict__ e2) {
  __shared__ float ss[NPER];
  __shared__ float sc[512];
  __shared__ int   sidx[512];
  __shared__ short rmp[NPER];
  __shared__ int   cnt[K];
  __shared__ float sdv[K];
  __shared__ int   srp[K];
  __shared__ int   sbuf[512];
  int g = blockIdx.x, tid = threadIdx.x;
  if (tid < NPER) { ss[tid] = spre[g * NPER + tid]; rmp[tid] = -1; }
  __syncthreads();
  if (tid < NPER) {
    const int* rpg = rp + g * (NPER + 1);
    int st = rpg[tid], en = rpg[tid + 1];
    const int2* ep = e2 + (size_t)g * EPGc;
    float di = dinv[g * NPER + tid];
    float acc = ss[tid] * di * di + sb[0];
    int e = st;
    for (; e + 4 <= en; e += 4) {
      int2 p0 = ep[e], p1 = ep[e + 1], p2 = ep[e + 2], p3 = ep[e + 3];
      acc += ss[p0.x - g * NPER] * __int_as_float(p0.y) +
             ss[p1.x - g * NPER] * __int_as_float(p1.y) +
             ss[p2.x - g * NPER] * __int_as_float(p2.y) +
             ss[p3.x - g * NPER] * __int_as_float(p3.y);
    }
    for (; e < en; ++e) { int2 pp = ep[e]; acc += ss[pp.x - g * NPER] * __int_as_float(pp.y); }
    sc[tid] = acc;
  } else {
    sc[tid] = -3.402823466e38f;
  }
  sidx[tid] = tid;
  __syncthreads();
  for (int kk = 2; kk <= 512; kk <<= 1) {
    for (int j = kk >> 1; j > 0; j >>= 1) {
      int i = tid, p = i ^ j;
      if (p > i) {
        bool up = ((i & kk) == 0);
        float si = sc[i], sp2 = sc[p];
        if (up ? (si < sp2) : (si > sp2)) {
          sc[i] = sp2; sc[p] = si;
          int t = sidx[i]; sidx[i] = sidx[p]; sidx[p] = t;
        }
      }
      __syncthreads();
    }
  }
  if (tid < K) {
    perm[g * K + tid] = g * NPER + sidx[tid];
    tsel[g * K + tid] = tanhf(sc[tid]);
    rmp[sidx[tid]] = (short)tid;
    cnt[tid] = 0;
  }
  __syncthreads();
  const int* sp = src + (size_t)g * EPGc;
  const int* dp = dst + (size_t)g * EPGc;
  for (int e = tid; e < EPGc; e += 512) {
    int s = rmp[sp[e] - g * NPER];
    int d = rmp[dp[e] - g * NPER];
    if ((s | d) >= 0) atomicAdd(&cnt[d], 1);
  }
  __syncthreads();
  int c = (tid < K) ? cnt[tid] : 0;
  if (tid < K) {
    float dv = 1.0f / sqrtf(1.0f + (float)c);
    sdv[tid] = dv;
    dinv2[g * K + tid] = dv;
  }
  sbuf[tid] = c;
  __syncthreads();
  for (int off = 1; off < 512; off <<= 1) {
    int t = (tid >= off) ? sbuf[tid - off] : 0;
    __syncthreads();
    sbuf[tid] += t;
    __syncthreads();
  }
  if (tid < K) { srp[tid] = sbuf[tid] - c; rp2[g * (K + 1) + tid] = sbuf[tid] - c; cnt[tid] = 0; }
  if (tid == 511) rp2[g * (K + 1) + K] = sbuf[511];
  __syncthreads();
  for (int e = tid; e < EPGc; e += 512) {
    int s = rmp[sp[e] - g * NPER];
    int d = rmp[dp[e] - g * NPER];
    if ((s | d) >= 0) {
      int pos = srp[d] + atomicAdd(&cnt[d], 1);
      e2[(size_t)g * EPGc + pos] = make_int2(g * K + s, __float_as_int(sdv[s] * sdv[d]));
    }
  }
}

// layer-2: score + topk + tanh (no edge rebuild)
template <int NPER, int K>
static __global__ __launch_bounds__(512) void k_topk2(const float* __restrict__ spre,
                                                      const float* __restrict__ dinv2,
                                                      const float* __restrict__ sb,
                                                      const int* __restrict__ rp2,
                                                      const int2* __restrict__ e2,
                                                      int* __restrict__ perm,
                                                      float* __restrict__ tsel) {
  __shared__ float ss[NPER];
  __shared__ float sc[512];
  __shared__ int   sidx[512];
  int g = blockIdx.x, tid = threadIdx.x;
  if (tid < NPER) ss[tid] = spre[g * NPER + tid];
  __syncthreads();
  if (tid < NPER) {
    const int* rpg = rp2 + g * (NPER + 1);
    int st = rpg[tid], en = rpg[tid + 1];
    const int2* ep = e2 + (size_t)g * EPGc;
    float di = dinv2[g * NPER + tid];
    float acc = ss[tid] * di * di + sb[0];
    int e = st;
    for (; e + 4 <= en; e += 4) {
      int2 p0 = ep[e], p1 = ep[e + 1], p2 = ep[e + 2], p3 = ep[e + 3];
      acc += ss[p0.x - g * NPER] * __int_as_float(p0.y) +
             ss[p1.x - g * NPER] * __int_as_float(p1.y) +
             ss[p2.x - g * NPER] * __int_as_float(p2.y) +
             ss[p3.x - g * NPER] * __int_as_float(p3.y);
    }
    for (; e < en; ++e) { int2 pp = ep[e]; acc += ss[pp.x - g * NPER] * __int_as_float(pp.y); }
    sc[tid] = acc;
  } else {
    sc[tid] = -3.402823466e38f;
  }
  sidx[tid] = tid;
  __syncthreads();
  for (int kk = 2; kk <= 512; kk <<= 1) {
    for (int j = kk >> 1; j > 0; j >>= 1) {
      int i = tid, p = i ^ j;
      if (p > i) {
        bool up = ((i & kk) == 0);
        float si = sc[i], sp2 = sc[p];
        if (up ? (si < sp2) : (si > sp2)) {
          sc[i] = sp2; sc[p] = si;
          int t = sidx[i]; sidx[i] = sidx[p]; sidx[p] = t;
        }
      }
      __syncthreads();
    }
  }
  if (tid < K) {
    perm[g * K + tid] = g * NPER + sidx[tid];
    tsel[g * K + tid] = tanhf(sc[tid]);
  }
}

// xp[j] = relu(bn(h[perm[j]] * tsel[j])), fused graph-sum via one atomic per
// (block, feature). tsel precomputed (no s-gather/tanhf here).
template <int NPER, int CH, bool WXP>
static __global__ __launch_bounds__(128) void k_poolbn(const float* __restrict__ h,
                                                       const float* __restrict__ tsel,
                                                       const int* __restrict__ perm,
                                                       const float* __restrict__ gg,
                                                       const float* __restrict__ bb,
                                                       const float* __restrict__ mm,
                                                       const float* __restrict__ vv,
                                                       float* __restrict__ xp,
                                                       float* __restrict__ pooledseg) {
  int g = blockIdx.x / CH, cidx = blockIdx.x - g * CH;
  int f = threadIdx.x;
  const int rows = (NPER + CH - 1) / CH;
  int r0 = cidx * rows, r1 = min(NPER, r0 + rows);
  if (r0 >= r1) return;
  float G = gg[f], Bb = bb[f], Mm = mm[f];
  float inv = 1.0f / sqrtf(vv[f] + EPSc);
  float acc = 0.f;
  for (int r = r0; r < r1; ++r) {
    int j = g * NPER + r;
    int old = perm[j];
    float val = h[(size_t)old * 128 + f] * tsel[j];
    float o = fmaxf(G * (val - Mm) * inv + Bb, 0.f);
    if (WXP) xp[(size_t)j * 128 + f] = o;
    acc += o;
  }
  atomicAdd(&pooledseg[g * 128 + f], acc);
}

static __global__ void k_final(const float* __restrict__ pooled,
                               const float* __restrict__ w0, const float* __restrict__ b0,
                               const float* __restrict__ w1, const float* __restrict__ b1,
                               const float* __restrict__ w2, const float* __restrict__ b2,
                               float* __restrict__ out) {
  int t = blockIdx.x * 256 + threadIdx.x;
  if (t >= Bg * DOUTc) return;
  int g = t / DOUTc, o = t - g * DOUTc;
  const float* p0 = pooled + g * 128;
  const float* p1 = pooled + Bg * 128 + g * 128;
  const float* p2 = pooled + 2 * Bg * 128 + g * 128;
  float acc = b0[o] + b1[o] + b2[o];
  for (int k = 0; k < 128; ++k)
    acc += p0[k] * w0[o * 128 + k] + p1[k] * w1[o * 128 + k] + p2[k] * w2[o * 128 + k];
  out[t] = acc;
}

extern "C" void kernel_launch(void* const* d_in, const int* in_sizes, int n_in,
                              void* d_out, int out_size, void* d_ws, size_t ws_size,
                              hipStream_t stream) {
  (void)in_sizes; (void)n_in; (void)out_size; (void)ws_size;
  const float* x    = (const float*)d_in[0];
  const int*   ei   = (const int*)d_in[1];
  const int*   src0 = ei;
  const int*   dst0 = ei + Etot;
  const float* c1W = (const float*)d_in[2];  const float* c1b = (const float*)d_in[3];
  const float* c2W = (const float*)d_in[4];  const float* c2b = (const float*)d_in[5];
  const float* s1W = (const float*)d_in[6];  const float* s1b = (const float*)d_in[7];
  const float* s2W = (const float*)d_in[8];  const float* s2b = (const float*)d_in[9];
  const float* bn1g = (const float*)d_in[10]; const float* bn1b = (const float*)d_in[11];
  const float* bn1m = (const float*)d_in[12]; const float* bn1v = (const float*)d_in[13];
  const float* bn2g = (const float*)d_in[14]; const float* bn2b = (const float*)d_in[15];
  const float* bn2m = (const float*)d_in[16]; const float* bn2v = (const float*)d_in[17];
  const float* l0W = (const float*)d_in[18]; const float* l0b = (const float*)d_in[19];
  const float* l1W = (const float*)d_in[20]; const float* l1b = (const float*)d_in[21];
  const float* l2W = (const float*)d_in[22]; const float* l2b = (const float*)d_in[23];
  float* out = (float*)d_out;

  char* p = (char*)d_ws;
  auto alloc = [&](size_t bytes) { char* q = p; p += (bytes + 255) & ~(size_t)255; return q; };
  float* h0    = (float*)alloc((size_t)N0c * 128 * 4);   // layer1 reuses as g1
  float* h1    = (float*)alloc((size_t)N0c * 128 * 4);   // layer1 reuses as h2
  float* xp1   = (float*)alloc((size_t)N1c * 128 * 4);
  float* dinv  = (float*)alloc((size_t)N0c * 4);
  float* dinv2 = (float*)alloc((size_t)N1c * 4);
  int*   rp    = (int*)alloc((size_t)Bg * (NPG + 1) * 4);
  int*   rp2   = (int*)alloc((size_t)Bg * (K1c + 1) * 4);
  int2*  e2    = (int2*)alloc((size_t)Etot * 8);
  float* spre  = (float*)alloc((size_t)N0c * 4);
  float* tsel  = (float*)alloc((size_t)N1c * 4);
  int*   perm  = (int*)alloc((size_t)N1c * 4);
  unsigned short* pk = (unsigned short*)alloc((size_t)65536 * 2);
  float* pooled= (float*)alloc((size_t)3 * Bg * 128 * 4);

  dim3 b256(256), b512(512), b128(128);

  // ---------------- layer 0 ----------------
  k_prep0<<<Bg, b512, 0, stream>>>(src0, dst0, c1W, c2W, pk, dinv, rp, e2, pooled);
  k_gemm3<<<N0c / 64, b256, 0, stream>>>(x, pk, h0, pooled);          // + fused xsum
  k_agg3<NPG, 64><<<128 * 64, b256, 0, stream>>>(h0, dinv, c1b, rp, e2, s1W, h1, spre);
  k_repool<NPG, K1c><<<Bg, b512, 0, stream>>>(spre, dinv, s1b, rp, src0, dst0,
                                              perm, tsel, dinv2, rp2, e2);
  k_poolbn<K1c, 16, true><<<Bg * 16, b128, 0, stream>>>(h1, tsel, perm, bn1g, bn1b,
                                                        bn1m, bn1v, xp1, pooled + Bg * 128);

  // ---------------- layer 1 ----------------
  float* g1 = h0;   // h0 dead after layer-0 agg
  float* h2 = h1;   // h1 dead after poolbn
  k_gemm3<<<N1c / 64, b256, 0, stream>>>(xp1, pk + 32768, g1, nullptr);
  k_agg3<K1c, 52><<<128 * 52, b256, 0, stream>>>(g1, dinv2, c2b, rp2, e2, s2W, h2, spre);
  k_topk2<K1c, K2c><<<Bg, b512, 0, stream>>>(spre, dinv2, s2b, rp2, e2, perm, tsel);
  k_poolbn<K2c, 16, false><<<Bg * 16, b128, 0, stream>>>(h2, tsel, perm, bn2g, bn2b,
                                                         bn2m, bn2v, nullptr,
                                                         pooled + 2 * Bg * 128);

  // ---------------- readout ----------------
  k_final<<<(Bg * DOUTc + 255) / 256, b256, 0, stream>>>(pooled, l0W, l0b, l1W, l1b, l2W, l2b, out);
}